// Round 1
// baseline (4885.899 us; speedup 1.0000x reference)
//
#include <hip/hip_runtime.h>
#include <hip/hip_bf16.h>
#include <math.h>

#define B_ 128
#define S_ 256
#define A_ 8
#define E_ 300
#define H_ 300
#define KPAD 320
#define GD 30      // blocks per direction
#define NB 48      // padded gate-cols per block (40 real)
#define UPB 10     // hidden units per block
#define WROW 648   // LDS row stride (ushorts) for W slice
#define NBLK 60

typedef unsigned short u16;
typedef __attribute__((ext_vector_type(8))) short short8;
typedef __attribute__((ext_vector_type(4))) float floatx4;

#define MFMA16(a, b, c) __builtin_amdgcn_mfma_f32_16x16x32_bf16((a), (b), (c), 0, 0, 0)

// ---- workspace layout (bytes) ----
static constexpr size_t oLens = 0;                       // mem_len[128], left_len[128], asp_len[128]
static constexpr size_t oCnt  = 1536;                    // barrier counter (256 B region)
static constexpr size_t oH    = 2048;                    // h panels bf16 [parity2][dir2][128][320] = 327680
static constexpr size_t oMemX = oH + 327680;             // x bf16 [dir2][128][256][320] = 41943040
static constexpr size_t oWp   = oMemX + 41943040;        // packed W bf16 [2][30][48][640] = 3686400
static constexpr size_t oBp   = oWp + 3686400;           // packed bias f32 [2][30][48] = 23040
static constexpr size_t oMemV = oBp + 23040;             // locationed memory v f32 [128][256][600] = 78643200
static constexpr size_t oIT   = oMemV + 78643200;        // i^T f32 [601][128] = 307712
static constexpr size_t oGi   = oIT + 307712;            // gi^T f32 [900][128] = 460800
static constexpr size_t oGh   = oGi + 460800;            // gh^T f32 [900][128] = 460800
static constexpr size_t oEt   = oGh + 460800;            // et^T f32 [300][128] = 153600
static constexpr size_t oSc   = oEt + 153600;            // scores f32 [128][256] = 131072
static constexpr size_t WS_NEED = oSc + 131072;          // ~126 MB

__device__ __forceinline__ u16 f2bf(float f) {
  union { float f; unsigned u; } v; v.f = f;
  unsigned r = (v.u + 0x7FFFu + ((v.u >> 16) & 1u)) >> 16;
  return (u16)r;
}
__device__ __forceinline__ float sigm(float x) { return 1.f / (1.f + __expf(-x)); }
__device__ __forceinline__ float tanh_f(float x) {
  x = fminf(15.f, fmaxf(-15.f, x));
  float e = __expf(2.f * x);
  return (e - 1.f) / (e + 1.f);
}

// ---------------- K1: lengths + zero init ----------------
__global__ __launch_bounds__(256) void init_kernel(const int* __restrict__ text,
                                                   const int* __restrict__ aspect,
                                                   const int* __restrict__ leftc,
                                                   char* __restrict__ ws) {
  const int bid = blockIdx.x, tid = threadIdx.x;
  if (bid == 0) {
    if (tid < B_) {
      int c = 0; const int* p = text + tid * S_;
      for (int s = 0; s < S_; ++s) c += (p[s] != 0);
      ((int*)(ws + oLens))[tid] = c;
    }
  } else if (bid == 1) {
    if (tid < B_) {
      int c = 0; const int* p = leftc + tid * S_;
      for (int s = 0; s < S_; ++s) c += (p[s] != 0);
      ((int*)(ws + oLens + 512))[tid] = c;
    }
  } else if (bid == 2) {
    if (tid < B_) {
      int c = 0; const int* p = aspect + tid * A_;
      for (int s = 0; s < A_; ++s) c += (p[s] != 0);
      ((int*)(ws + oLens + 1024))[tid] = c;
    }
  } else {
    const int CW = 64, HW = 327680 / 4, EW = 153600 / 4;
    const int total = CW + HW + EW;
    for (int i = (bid - 3) * 256 + tid; i < total; i += 64 * 256) {
      if (i < CW)            ((unsigned*)(ws + oCnt))[i] = 0u;
      else if (i < CW + HW)  ((unsigned*)(ws + oH))[i - CW] = 0u;
      else                   ((unsigned*)(ws + oEt))[i - CW - HW] = 0u;
    }
  }
}

// ---------------- K2: weight/bias pre-pack to bf16 ----------------
__global__ __launch_bounds__(256) void pack_kernel(
    const float* __restrict__ WihF, const float* __restrict__ WhhF,
    const float* __restrict__ bihF, const float* __restrict__ bhhF,
    const float* __restrict__ WihB, const float* __restrict__ WhhB,
    const float* __restrict__ bihB, const float* __restrict__ bhhB,
    char* __restrict__ ws) {
  const int WTOT = 2 * GD * NB * 640;
  int idx = blockIdx.x * 256 + threadIdx.x;
  if (idx < WTOT) {
    int k = idx % 640;
    int n = (idx / 640) % NB;
    int bg = (idx / (640 * NB)) % GD;
    int dir = idx / (640 * NB * GD);
    float v = 0.f;
    if (n < 40) {
      int col = (n & 3) * 300 + bg * UPB + (n >> 2);  // gate*300 + unit
      const float* Wih = dir ? WihB : WihF;
      const float* Whh = dir ? WhhB : WhhF;
      if (k < 300)               v = Wih[(size_t)col * 300 + k];
      else if (k >= 320 && k < 620) v = Whh[(size_t)col * 300 + (k - 320)];
    }
    ((u16*)(ws + oWp))[idx] = f2bf(v);
  } else {
    int j = idx - WTOT;
    if (j < 2 * GD * NB) {
      int n = j % NB; int bg = (j / NB) % GD; int dir = j / (NB * GD);
      float v = 0.f;
      if (n < 40) {
        int col = (n & 3) * 300 + bg * UPB + (n >> 2);
        v = (dir ? bihB : bihF)[col] + (dir ? bhhB : bhhF)[col];
      }
      ((float*)(ws + oBp))[j] = v;
    }
  }
}

// ---------------- K3: embedding gather (bwd dir pre-reversed) ----------------
__global__ __launch_bounds__(KPAD) void gather_kernel(const int* __restrict__ text,
                                                      const float* __restrict__ emb,
                                                      char* __restrict__ ws) {
  const int bid = blockIdx.x;
  const int t = bid & 255;
  const int b = (bid >> 8) & 127;
  const int dir = bid >> 15;
  const int len = ((const int*)(ws + oLens))[b];
  const int tp = (dir == 0) ? t : ((t < len) ? (len - 1 - t) : t);
  const int tok = text[b * S_ + tp];
  u16* dst = (u16*)(ws + oMemX) + ((size_t)((dir * B_ + b) * S_ + t)) * KPAD;
  const float* src = emb + (size_t)tok * E_;
  const int k = threadIdx.x;
  float v = (k < E_) ? src[k] : 0.f;
  dst[k] = f2bf(v);
}

// ---------------- K4: persistent BiLSTM ----------------
__global__ __launch_bounds__(512, 1) void lstm_kernel(char* __restrict__ ws) {
  const int dir = (int)blockIdx.x / GD;
  const int bg  = (int)blockIdx.x % GD;
  const int tid = threadIdx.x;
  const int wv = tid >> 6;
  const int lane = tid & 63;
  const int quad = lane >> 4;
  const int l16 = lane & 15;

  const u16* __restrict__ Wp = (const u16*)(ws + oWp) + (size_t)(dir * GD + bg) * NB * 640;
  const float* __restrict__ Bpk = (const float*)(ws + oBp) + (dir * GD + bg) * NB;
  const u16* __restrict__ memx = (const u16*)(ws + oMemX) + (size_t)dir * B_ * S_ * KPAD;
  u16* __restrict__ hbuf = (u16*)(ws + oH);
  float* __restrict__ memv = (float*)(ws + oMemV);
  const int* __restrict__ mlen = (const int*)(ws + oLens);
  const int* __restrict__ llen = (const int*)(ws + oLens + 512);
  const int* __restrict__ alen = (const int*)(ws + oLens + 1024);
  int* cnt = (int*)(ws + oCnt);

  __shared__ __align__(16) u16 Wlds[NB * WROW];
  __shared__ float gatesLds[128 * 49];
  __shared__ float cS[1280];
  __shared__ float hS[1280];
  __shared__ float biasS[NB];
  __shared__ int lenS[128], llS[128], alS[128];

  for (int i = tid; i < NB * 640; i += 512) {
    int n = i / 640;
    Wlds[n * WROW + (i - n * 640)] = Wp[i];
  }
  for (int i = tid; i < 1280; i += 512) { cS[i] = 0.f; hS[i] = 0.f; }
  if (tid < NB) biasS[tid] = Bpk[tid];
  if (tid < 128) { lenS[tid] = mlen[tid]; llS[tid] = llen[tid]; alS[tid] = alen[tid]; }
  __syncthreads();

  const int row = wv * 16 + l16;  // batch row this lane covers in A-frags
  const u16* wbase = Wlds + l16 * WROW + quad * 8;

  floatx4 acc0 = {0.f, 0.f, 0.f, 0.f}, acc1 = acc0, acc2 = acc0;

  // x-part of t = 0
  {
    const u16* xr = memx + ((size_t)row * S_) * KPAD + quad * 8;
    #pragma unroll
    for (int kk = 0; kk < KPAD; kk += 32) {
      short8 a = *(const short8*)(xr + kk);
      acc0 = MFMA16(a, *(const short8*)(wbase + kk), acc0);
      acc1 = MFMA16(a, *(const short8*)(wbase + 16 * WROW + kk), acc1);
      acc2 = MFMA16(a, *(const short8*)(wbase + 32 * WROW + kk), acc2);
    }
  }

  for (int t = 0; t < S_; ++t) {
    if (t > 0) {
      if (tid == 0) {
        const int target = NBLK * t;
        while (__hip_atomic_load(cnt, __ATOMIC_ACQUIRE, __HIP_MEMORY_SCOPE_AGENT) < target)
          __builtin_amdgcn_s_sleep(1);
      }
      __syncthreads();
    }
    // h-part of step t
    {
      const u16* hr = hbuf + (((size_t)(t & 1) * 2 + dir) * B_ + row) * KPAD + quad * 8;
      #pragma unroll
      for (int kk = 0; kk < KPAD; kk += 32) {
        short8 a = *(const short8*)(hr + kk);
        acc0 = MFMA16(a, *(const short8*)(wbase + 320 + kk), acc0);
        acc1 = MFMA16(a, *(const short8*)(wbase + 16 * WROW + 320 + kk), acc1);
        acc2 = MFMA16(a, *(const short8*)(wbase + 32 * WROW + 320 + kk), acc2);
      }
    }
    // stage gate pre-activations to LDS  (C layout: col=lane&15, row=quad*4+reg)
    {
      const int rbase = wv * 16 + quad * 4;
      #pragma unroll
      for (int r = 0; r < 4; ++r) {
        gatesLds[(rbase + r) * 49 + l16] = acc0[r];
        gatesLds[(rbase + r) * 49 + 16 + l16] = acc1[r];
        gatesLds[(rbase + r) * 49 + 32 + l16] = acc2[r];
      }
    }
    __syncthreads();
    // elementwise LSTM cell + outputs
    const int nxt = (t + 1) & 1;
    for (int item = tid; item < 1280; item += 512) {
      const int b = item / 10;
      const int ul = item - b * 10;
      const int len = lenS[b];
      const bool m = (t < len);
      float gi = gatesLds[b * 49 + ul * 4 + 0] + biasS[ul * 4 + 0];
      float gf = gatesLds[b * 49 + ul * 4 + 1] + biasS[ul * 4 + 1];
      float gg = gatesLds[b * 49 + ul * 4 + 2] + biasS[ul * 4 + 2];
      float go = gatesLds[b * 49 + ul * 4 + 3] + biasS[ul * 4 + 3];
      float ig = sigm(gi), fg = sigm(gf), gt = tanh_f(gg), og = sigm(go);
      float cOld = cS[item], hOld = hS[item];
      float cNew = fg * cOld + ig * gt;
      float hNew = og * tanh_f(cNew);
      float cK = m ? cNew : cOld;
      float hK = m ? hNew : hOld;
      cS[item] = cK; hS[item] = hK;
      const int u = bg * UPB + ul;
      hbuf[(((size_t)nxt * 2 + dir) * B_ + b) * KPAD + u] = f2bf(hK);
      int pos = (dir == 0) ? t : (m ? (len - 1 - t) : t);
      float ml = (float)len, ll = (float)llS[b], al = (float)alS[b];
      float p = (float)pos;
      float wl;
      if (p < ll) wl = 1.f - (ll - p) / ml;
      else if ((p >= ll + al) && (p < ml)) wl = 1.f - (p - ll - al + 1.f) / ml;
      else wl = 1.f;
      float hOut = m ? hNew : 0.f;
      memv[((size_t)b * S_ + pos) * 600 + dir * 300 + u] = hOut * wl;
    }
    __threadfence();
    __syncthreads();
    if (tid == 0) atomicAdd(cnt, 1);
    // prefetch next step's x-part (overlaps stragglers before next wait)
    acc0 = (floatx4){0.f, 0.f, 0.f, 0.f}; acc1 = acc0; acc2 = acc0;
    if (t + 1 < S_) {
      const u16* xr = memx + ((size_t)row * S_ + (t + 1)) * KPAD + quad * 8;
      #pragma unroll
      for (int kk = 0; kk < KPAD; kk += 32) {
        short8 a = *(const short8*)(xr + kk);
        acc0 = MFMA16(a, *(const short8*)(wbase + kk), acc0);
        acc1 = MFMA16(a, *(const short8*)(wbase + 16 * WROW + kk), acc1);
        acc2 = MFMA16(a, *(const short8*)(wbase + 32 * WROW + kk), acc2);
      }
    }
  }
}

// ---------------- K5: attention scores ----------------
__global__ __launch_bounds__(256) void score_kernel(const float* __restrict__ attW,
                                                    char* __restrict__ ws) {
  const int bid = blockIdx.x;
  const int b = bid >> 1, sh = bid & 1;
  const int tid = threadIdx.x, wv = tid >> 6, lane = tid & 63;
  __shared__ float aW[601];
  for (int i = tid; i < 601; i += 256) aW[i] = attW[i];
  const float* memv = (const float*)(ws + oMemV) + (size_t)b * S_ * 600;
  const float ml = (float)((const int*)(ws + oLens))[b];
  const float ll = (float)((const int*)(ws + oLens + 512))[b];
  const float al = (float)((const int*)(ws + oLens + 1024))[b];
  __syncthreads();
  float* scg = (float*)(ws + oSc) + b * S_;
  for (int s = sh * 128 + wv; s < sh * 128 + 128; s += 4) {
    const float* rowp = memv + (size_t)s * 600;
    float acc = 0.f;
    for (int d = lane; d < 600; d += 64) acc += rowp[d] * aW[d];
    for (int off = 32; off; off >>= 1) acc += __shfl_xor(acc, off);
    if (lane == 0) {
      float p = (float)s;
      bool inl = p < ll;
      bool inr = (p >= ll + al) && (p < ml);
      float u = inl ? (p - ll) : (inr ? (p - ll - al + 1.f) : 0.f);
      scg[s] = acc + u * aW[600];
    }
  }
}

// ---------------- K6: softmax + weighted sum -> i^T ----------------
__global__ __launch_bounds__(256) void attn_kernel(char* __restrict__ ws) {
  const int bid = blockIdx.x;
  const int b = bid >> 1, dh = bid & 1;
  const int tid = threadIdx.x, wv = tid >> 6, lane = tid & 63;
  __shared__ float alpha[256];
  __shared__ float red[8];
  const float* scg = (const float*)(ws + oSc) + b * S_;
  float v = scg[tid];
  float mx = v;
  for (int off = 32; off; off >>= 1) mx = fmaxf(mx, __shfl_xor(mx, off));
  if (lane == 0) red[wv] = mx;
  __syncthreads();
  mx = fmaxf(fmaxf(red[0], red[1]), fmaxf(red[2], red[3]));
  float e = __expf(v - mx);
  float sm = e;
  for (int off = 32; off; off >>= 1) sm += __shfl_xor(sm, off);
  if (lane == 0) red[4 + wv] = sm;
  __syncthreads();
  float tot = red[4] + red[5] + red[6] + red[7];
  alpha[tid] = e / tot;
  const float ml = (float)((const int*)(ws + oLens))[b];
  const float ll = (float)((const int*)(ws + oLens + 512))[b];
  const float al = (float)((const int*)(ws + oLens + 1024))[b];
  __syncthreads();
  const float* memv = (const float*)(ws + oMemV) + (size_t)b * S_ * 600;
  float* iT = (float*)(ws + oIT);
  const int d0 = dh * 301, d1 = dh ? 601 : 301;
  for (int d = d0 + tid; d < d1; d += 256) {
    float acc = 0.f;
    if (d < 600) {
      for (int s = 0; s < 256; ++s) acc += alpha[s] * memv[(size_t)s * 600 + d];
    } else {
      for (int s = 0; s < 256; ++s) {
        float p = (float)s;
        bool inl = p < ll;
        bool inr = (p >= ll + al) && (p < ml);
        float u = inl ? (p - ll) : (inr ? (p - ll - al + 1.f) : 0.f);
        acc += alpha[s] * u;
      }
    }
    iT[d * 128 + b] = acc;
  }
}

// ---------------- K7: GRU gi (once) ----------------
__global__ __launch_bounds__(256) void gi_kernel(const float* __restrict__ Wih,
                                                 const float* __restrict__ bih,
                                                 char* __restrict__ ws) {
  int idx = blockIdx.x * 256 + threadIdx.x;
  int r = idx >> 7, b = idx & 127;
  if (r >= 900) return;
  const float* iT = (const float*)(ws + oIT);
  const float* wr = Wih + (size_t)r * 601;
  float acc = bih[r];
  for (int d = 0; d < 601; ++d) acc += iT[d * 128 + b] * wr[d];
  ((float*)(ws + oGi))[r * 128 + b] = acc;
}

// ---------------- K8: GRU gh (per hop) ----------------
__global__ __launch_bounds__(256) void gh_kernel(const float* __restrict__ Whh,
                                                 const float* __restrict__ bhh,
                                                 char* __restrict__ ws) {
  int idx = blockIdx.x * 256 + threadIdx.x;
  int r = idx >> 7, b = idx & 127;
  if (r >= 900) return;
  const float* et = (const float*)(ws + oEt);
  const float* wr = Whh + (size_t)r * 300;
  float acc = bhh[r];
  for (int u = 0; u < 300; ++u) acc += et[u * 128 + b] * wr[u];
  ((float*)(ws + oGh))[r * 128 + b] = acc;
}

// ---------------- K9: GRU update (per hop) ----------------
__global__ __launch_bounds__(256) void up_kernel(char* __restrict__ ws) {
  int idx = blockIdx.x * 256 + threadIdx.x;
  int u = idx >> 7, b = idx & 127;
  if (u >= 300) return;
  const float* gi = (const float*)(ws + oGi);
  const float* gh = (const float*)(ws + oGh);
  float* et = (float*)(ws + oEt);
  float rr = sigm(gi[u * 128 + b] + gh[u * 128 + b]);
  float zz = sigm(gi[(300 + u) * 128 + b] + gh[(300 + u) * 128 + b]);
  float nn = tanh_f(gi[(600 + u) * 128 + b] + rr * gh[(600 + u) * 128 + b]);
  float old = et[u * 128 + b];
  et[u * 128 + b] = (1.f - zz) * nn + zz * old;
}

// ---------------- K10: dense head ----------------
__global__ __launch_bounds__(384) void dense_kernel(const float* __restrict__ dW,
                                                    const float* __restrict__ dB,
                                                    float* __restrict__ out,
                                                    const char* __restrict__ ws) {
  int tid = threadIdx.x;
  if (tid >= 384) return;
  int b = tid / 3, c = tid - 3 * (tid / 3);
  const float* et = (const float*)(ws + oEt);
  float acc = dB[c];
  const float* wr = dW + c * 300;
  for (int u = 0; u < 300; ++u) acc += et[u * 128 + b] * wr[u];
  out[b * 3 + c] = acc;
}

extern "C" void kernel_launch(void* const* d_in, const int* in_sizes, int n_in,
                              void* d_out, int out_size, void* d_ws, size_t ws_size,
                              hipStream_t stream) {
  const int* text = (const int*)d_in[0];
  const int* aspect = (const int*)d_in[1];
  const int* leftc = (const int*)d_in[2];
  const float* emb = (const float*)d_in[3];
  const float* WihF = (const float*)d_in[4];
  const float* WhhF = (const float*)d_in[5];
  const float* bihF = (const float*)d_in[6];
  const float* bhhF = (const float*)d_in[7];
  const float* WihB = (const float*)d_in[8];
  const float* WhhB = (const float*)d_in[9];
  const float* bihB = (const float*)d_in[10];
  const float* bhhB = (const float*)d_in[11];
  const float* attW = (const float*)d_in[12];
  const float* gruWih = (const float*)d_in[14];
  const float* gruWhh = (const float*)d_in[15];
  const float* gruBih = (const float*)d_in[16];
  const float* gruBhh = (const float*)d_in[17];
  const float* denseW = (const float*)d_in[18];
  const float* denseB = (const float*)d_in[19];
  float* out = (float*)d_out;
  char* ws = (char*)d_ws;
  if (ws_size < WS_NEED) return;

  init_kernel<<<67, 256, 0, stream>>>(text, aspect, leftc, ws);
  pack_kernel<<<7212, 256, 0, stream>>>(WihF, WhhF, bihF, bhhF, WihB, WhhB, bihB, bhhB, ws);
  gather_kernel<<<2 * B_ * S_, KPAD, 0, stream>>>(text, emb, ws);
  lstm_kernel<<<NBLK, 512, 0, stream>>>(ws);
  score_kernel<<<2 * B_, 256, 0, stream>>>(attW, ws);
  attn_kernel<<<2 * B_, 256, 0, stream>>>(ws);
  gi_kernel<<<450, 256, 0, stream>>>(gruWih, gruBih, ws);
  for (int h = 0; h < 3; ++h) {
    gh_kernel<<<450, 256, 0, stream>>>(gruWhh, gruBhh, ws);
    up_kernel<<<150, 256, 0, stream>>>(ws);
  }
  dense_kernel<<<1, 384, 0, stream>>>(denseW, denseB, out, ws);
}

// Round 2
// 2730.262 us; speedup vs baseline: 1.7895x; 1.7895x over previous
//
#include <hip/hip_runtime.h>
#include <hip/hip_bf16.h>
#include <math.h>

#define B_ 128
#define S_ 256
#define A_ 8
#define E_ 300
#define H_ 300
#define KPAD 320
#define GD 30      // blocks per direction
#define NB 48      // padded gate-cols per block (40 real)
#define UPB 10     // hidden units per block
#define WROW 648   // LDS row stride (ushorts) for W slice
#define NBLK 60

typedef unsigned short u16;
typedef unsigned int u32;
typedef unsigned long long u64;
typedef __attribute__((ext_vector_type(8))) short short8;
typedef __attribute__((ext_vector_type(4))) float floatx4;

#define MFMA16(a, b, c) __builtin_amdgcn_mfma_f32_16x16x32_bf16((a), (b), (c), 0, 0, 0)

// ---- workspace layout (bytes) ----
static constexpr size_t oLens = 0;                       // mem_len[128], left_len[128], asp_len[128]
static constexpr size_t oCnt  = 1536;                    // barrier counters (512 B region, one per dir 256B apart)
static constexpr size_t oH    = 2048;                    // h panels bf16 [parity2][dir2][128][320] = 327680
static constexpr size_t oMemX = oH + 327680;             // x bf16 [dir2][128][256][320] = 41943040
static constexpr size_t oWp   = oMemX + 41943040;        // packed W bf16 [2][30][48][640] = 3686400
static constexpr size_t oBp   = oWp + 3686400;           // packed bias f32 [2][30][48] = 23040
static constexpr size_t oMemV = oBp + 23040;             // locationed memory v f32 [128][256][600] = 78643200
static constexpr size_t oIT   = oMemV + 78643200;        // i^T f32 [601][128] = 307712
static constexpr size_t oGi   = oIT + 307712;            // gi^T f32 [900][128] = 460800
static constexpr size_t oGh   = oGi + 460800;            // gh^T f32 [900][128] = 460800
static constexpr size_t oEt   = oGh + 460800;            // et^T f32 [300][128] = 153600
static constexpr size_t oSc   = oEt + 153600;            // scores f32 [128][256] = 131072
static constexpr size_t WS_NEED = oSc + 131072;          // ~126 MB

__device__ __forceinline__ u16 f2bf(float f) {
  union { float f; unsigned u; } v; v.f = f;
  unsigned r = (v.u + 0x7FFFu + ((v.u >> 16) & 1u)) >> 16;
  return (u16)r;
}
__device__ __forceinline__ float sigm(float x) { return 1.f / (1.f + __expf(-x)); }
__device__ __forceinline__ float tanh_f(float x) {
  x = fminf(15.f, fmaxf(-15.f, x));
  float e = __expf(2.f * x);
  return (e - 1.f) / (e + 1.f);
}

// ---------------- K1: lengths + zero init ----------------
__global__ __launch_bounds__(256) void init_kernel(const int* __restrict__ text,
                                                   const int* __restrict__ aspect,
                                                   const int* __restrict__ leftc,
                                                   char* __restrict__ ws) {
  const int bid = blockIdx.x, tid = threadIdx.x;
  if (bid == 0) {
    if (tid < B_) {
      int c = 0; const int* p = text + tid * S_;
      for (int s = 0; s < S_; ++s) c += (p[s] != 0);
      ((int*)(ws + oLens))[tid] = c;
    }
  } else if (bid == 1) {
    if (tid < B_) {
      int c = 0; const int* p = leftc + tid * S_;
      for (int s = 0; s < S_; ++s) c += (p[s] != 0);
      ((int*)(ws + oLens + 512))[tid] = c;
    }
  } else if (bid == 2) {
    if (tid < B_) {
      int c = 0; const int* p = aspect + tid * A_;
      for (int s = 0; s < A_; ++s) c += (p[s] != 0);
      ((int*)(ws + oLens + 1024))[tid] = c;
    }
  } else {
    const int CW = 128, HW = 327680 / 4, EW = 153600 / 4;
    const int total = CW + HW + EW;
    for (int i = (bid - 3) * 256 + tid; i < total; i += 64 * 256) {
      if (i < CW)            ((unsigned*)(ws + oCnt))[i] = 0u;
      else if (i < CW + HW)  ((unsigned*)(ws + oH))[i - CW] = 0u;
      else                   ((unsigned*)(ws + oEt))[i - CW - HW] = 0u;
    }
  }
}

// ---------------- K2: weight/bias pre-pack to bf16 ----------------
__global__ __launch_bounds__(256) void pack_kernel(
    const float* __restrict__ WihF, const float* __restrict__ WhhF,
    const float* __restrict__ bihF, const float* __restrict__ bhhF,
    const float* __restrict__ WihB, const float* __restrict__ WhhB,
    const float* __restrict__ bihB, const float* __restrict__ bhhB,
    char* __restrict__ ws) {
  const int WTOT = 2 * GD * NB * 640;
  int idx = blockIdx.x * 256 + threadIdx.x;
  if (idx < WTOT) {
    int k = idx % 640;
    int n = (idx / 640) % NB;
    int bg = (idx / (640 * NB)) % GD;
    int dir = idx / (640 * NB * GD);
    float v = 0.f;
    if (n < 40) {
      int col = (n & 3) * 300 + bg * UPB + (n >> 2);  // gate*300 + unit
      const float* Wih = dir ? WihB : WihF;
      const float* Whh = dir ? WhhB : WhhF;
      if (k < 300)               v = Wih[(size_t)col * 300 + k];
      else if (k >= 320 && k < 620) v = Whh[(size_t)col * 300 + (k - 320)];
    }
    ((u16*)(ws + oWp))[idx] = f2bf(v);
  } else {
    int j = idx - WTOT;
    if (j < 2 * GD * NB) {
      int n = j % NB; int bg = (j / NB) % GD; int dir = j / (NB * GD);
      float v = 0.f;
      if (n < 40) {
        int col = (n & 3) * 300 + bg * UPB + (n >> 2);
        v = (dir ? bihB : bihF)[col] + (dir ? bhhB : bhhF)[col];
      }
      ((float*)(ws + oBp))[j] = v;
    }
  }
}

// ---------------- K3: embedding gather (bwd dir pre-reversed) ----------------
__global__ __launch_bounds__(KPAD) void gather_kernel(const int* __restrict__ text,
                                                      const float* __restrict__ emb,
                                                      char* __restrict__ ws) {
  const int bid = blockIdx.x;
  const int t = bid & 255;
  const int b = (bid >> 8) & 127;
  const int dir = bid >> 15;
  const int len = ((const int*)(ws + oLens))[b];
  const int tp = (dir == 0) ? t : ((t < len) ? (len - 1 - t) : t);
  const int tok = text[b * S_ + tp];
  u16* dst = (u16*)(ws + oMemX) + ((size_t)((dir * B_ + b) * S_ + t)) * KPAD;
  const float* src = emb + (size_t)tok * E_;
  const int k = threadIdx.x;
  float v = (k < E_) ? src[k] : 0.f;
  dst[k] = f2bf(v);
}

// ---------------- K4: persistent BiLSTM ----------------
// h exchange + barrier counter via RELAXED agent-scope atomics (sc1 -> served
// at the coherence point, bypassing the non-coherent per-XCD L2). No
// __threadfence / acquire-atomic polling => no buffer_wbl2 / buffer_inv storms.
__global__ __launch_bounds__(512, 1) void lstm_kernel(char* __restrict__ ws) {
  const int dir = (int)blockIdx.x / GD;
  const int bg  = (int)blockIdx.x % GD;
  const int tid = threadIdx.x;
  const int wv = tid >> 6;
  const int lane = tid & 63;
  const int quad = lane >> 4;
  const int l16 = lane & 15;

  const u16* __restrict__ Wp = (const u16*)(ws + oWp) + (size_t)(dir * GD + bg) * NB * 640;
  const float* __restrict__ Bpk = (const float*)(ws + oBp) + (dir * GD + bg) * NB;
  const u16* __restrict__ memx = (const u16*)(ws + oMemX) + (size_t)dir * B_ * S_ * KPAD;
  u64* __restrict__ hb64 = (u64*)(ws + oH);
  u32* __restrict__ hb32 = (u32*)(ws + oH);
  float* __restrict__ memv = (float*)(ws + oMemV);
  const int* __restrict__ mlen = (const int*)(ws + oLens);
  const int* __restrict__ llen = (const int*)(ws + oLens + 512);
  const int* __restrict__ alen = (const int*)(ws + oLens + 1024);
  int* cnt = (int*)(ws + oCnt) + dir * 64;   // per-direction barrier, 256B apart

  __shared__ __align__(16) u16 Wlds[NB * WROW];
  __shared__ float gatesLds[128 * 49];
  __shared__ float cS[1280];
  __shared__ float hS[1280];
  __shared__ float biasS[NB];
  __shared__ int lenS[128], llS[128], alS[128];

  for (int i = tid; i < NB * 640; i += 512) {
    int n = i / 640;
    Wlds[n * WROW + (i - n * 640)] = Wp[i];
  }
  for (int i = tid; i < 1280; i += 512) { cS[i] = 0.f; hS[i] = 0.f; }
  if (tid < NB) biasS[tid] = Bpk[tid];
  if (tid < 128) { lenS[tid] = mlen[tid]; llS[tid] = llen[tid]; alS[tid] = alen[tid]; }
  __syncthreads();

  const int row = wv * 16 + l16;  // batch row this lane covers in A-frags
  const u16* wbase = Wlds + l16 * WROW + quad * 8;

  floatx4 acc0 = {0.f, 0.f, 0.f, 0.f}, acc1 = acc0, acc2 = acc0;

  // x-part of t = 0
  {
    const u16* xr = memx + ((size_t)row * S_) * KPAD + quad * 8;
    #pragma unroll
    for (int kk = 0; kk < KPAD; kk += 32) {
      short8 a = *(const short8*)(xr + kk);
      acc0 = MFMA16(a, *(const short8*)(wbase + kk), acc0);
      acc1 = MFMA16(a, *(const short8*)(wbase + 16 * WROW + kk), acc1);
      acc2 = MFMA16(a, *(const short8*)(wbase + 32 * WROW + kk), acc2);
    }
  }

  for (int t = 0; t < S_; ++t) {
    if (t > 0) {
      if (tid == 0) {
        const int target = GD * t;
        while (__hip_atomic_load(cnt, __ATOMIC_RELAXED, __HIP_MEMORY_SCOPE_AGENT) < target) { }
      }
      __syncthreads();
      __builtin_amdgcn_fence(__ATOMIC_ACQUIRE, "workgroup");  // compiler ordering; no cache ops
    }
    // h-part of step t: coherent (sc1) loads straight from the exchange buffer
    {
      const u64* hq = hb64 + (((size_t)(t & 1) * 2 + dir) * B_ + row) * 80 + quad * 2;
      #pragma unroll
      for (int kk = 0; kk < 10; ++kk) {
        union { u64 q[2]; short8 v; } a;
        a.q[0] = __hip_atomic_load(hq + kk * 8 + 0, __ATOMIC_RELAXED, __HIP_MEMORY_SCOPE_AGENT);
        a.q[1] = __hip_atomic_load(hq + kk * 8 + 1, __ATOMIC_RELAXED, __HIP_MEMORY_SCOPE_AGENT);
        const int ko = kk * 32 + 320;
        acc0 = MFMA16(a.v, *(const short8*)(wbase + ko), acc0);
        acc1 = MFMA16(a.v, *(const short8*)(wbase + 16 * WROW + ko), acc1);
        acc2 = MFMA16(a.v, *(const short8*)(wbase + 32 * WROW + ko), acc2);
      }
    }
    // stage gate pre-activations to LDS  (C layout: col=lane&15, row=quad*4+reg)
    {
      const int rbase = wv * 16 + quad * 4;
      #pragma unroll
      for (int r = 0; r < 4; ++r) {
        gatesLds[(rbase + r) * 49 + l16] = acc0[r];
        gatesLds[(rbase + r) * 49 + 16 + l16] = acc1[r];
        gatesLds[(rbase + r) * 49 + 32 + l16] = acc2[r];
      }
    }
    __syncthreads();
    // elementwise LSTM cell + outputs (pair-of-units per item -> packed u32 h store)
    const int nxt = (t + 1) & 1;
    for (int it = tid; it < 640; it += 512) {
      const int b = it / 5;
      const int pl = it - b * 5;
      const int u0 = pl * 2;
      const int len = lenS[b];
      const bool m = (t < len);
      const float* gp = gatesLds + b * 49 + u0 * 4;
      const float* bp = biasS + u0 * 4;
      float h0K, h1K, h0N, h1N;
      {
        float ig = sigm(gp[0] + bp[0]);
        float fg = sigm(gp[1] + bp[1]);
        float gt = tanh_f(gp[2] + bp[2]);
        float og = sigm(gp[3] + bp[3]);
        float cOld = cS[b * 10 + u0], hOld = hS[b * 10 + u0];
        float cNew = fg * cOld + ig * gt;
        float hNew = og * tanh_f(cNew);
        cS[b * 10 + u0] = m ? cNew : cOld;
        h0K = m ? hNew : hOld;
        hS[b * 10 + u0] = h0K;
        h0N = m ? hNew : 0.f;
      }
      {
        float ig = sigm(gp[4] + bp[4]);
        float fg = sigm(gp[5] + bp[5]);
        float gt = tanh_f(gp[6] + bp[6]);
        float og = sigm(gp[7] + bp[7]);
        float cOld = cS[b * 10 + u0 + 1], hOld = hS[b * 10 + u0 + 1];
        float cNew = fg * cOld + ig * gt;
        float hNew = og * tanh_f(cNew);
        cS[b * 10 + u0 + 1] = m ? cNew : cOld;
        h1K = m ? hNew : hOld;
        hS[b * 10 + u0 + 1] = h1K;
        h1N = m ? hNew : 0.f;
      }
      u32 packed = (u32)f2bf(h0K) | ((u32)f2bf(h1K) << 16);
      __hip_atomic_store(&hb32[(((size_t)nxt * 2 + dir) * B_ + b) * 160 + bg * 5 + pl],
                         packed, __ATOMIC_RELAXED, __HIP_MEMORY_SCOPE_AGENT);
      int pos = (dir == 0) ? t : (m ? (len - 1 - t) : t);
      float ml = (float)len, ll = (float)llS[b], al = (float)alS[b];
      float p = (float)pos;
      float wl;
      if (p < ll) wl = 1.f - (ll - p) / ml;
      else if ((p >= ll + al) && (p < ml)) wl = 1.f - (p - ll - al + 1.f) / ml;
      else wl = 1.f;
      float2 vv = make_float2(h0N * wl, h1N * wl);
      *(float2*)&memv[((size_t)b * S_ + pos) * 600 + dir * 300 + bg * UPB + u0] = vv;
    }
    __builtin_amdgcn_fence(__ATOMIC_RELEASE, "workgroup");  // compiler ordering; no cache ops
    __syncthreads();                                        // drains vmcnt(0) per wave -> h stores acked at L3
    if (tid == 0)
      __hip_atomic_fetch_add(cnt, 1, __ATOMIC_RELAXED, __HIP_MEMORY_SCOPE_AGENT);
    // prefetch next step's x-part (overlaps stragglers before next wait)
    acc0 = (floatx4){0.f, 0.f, 0.f, 0.f}; acc1 = acc0; acc2 = acc0;
    if (t + 1 < S_) {
      const u16* xr = memx + ((size_t)row * S_ + (t + 1)) * KPAD + quad * 8;
      #pragma unroll
      for (int kk = 0; kk < KPAD; kk += 32) {
        short8 a = *(const short8*)(xr + kk);
        acc0 = MFMA16(a, *(const short8*)(wbase + kk), acc0);
        acc1 = MFMA16(a, *(const short8*)(wbase + 16 * WROW + kk), acc1);
        acc2 = MFMA16(a, *(const short8*)(wbase + 32 * WROW + kk), acc2);
      }
    }
  }
}

// ---------------- K5: attention scores ----------------
__global__ __launch_bounds__(256) void score_kernel(const float* __restrict__ attW,
                                                    char* __restrict__ ws) {
  const int bid = blockIdx.x;
  const int b = bid >> 1, sh = bid & 1;
  const int tid = threadIdx.x, wv = tid >> 6, lane = tid & 63;
  __shared__ float aW[601];
  for (int i = tid; i < 601; i += 256) aW[i] = attW[i];
  const float* memv = (const float*)(ws + oMemV) + (size_t)b * S_ * 600;
  const float ml = (float)((const int*)(ws + oLens))[b];
  const float ll = (float)((const int*)(ws + oLens + 512))[b];
  const float al = (float)((const int*)(ws + oLens + 1024))[b];
  __syncthreads();
  float* scg = (float*)(ws + oSc) + b * S_;
  for (int s = sh * 128 + wv; s < sh * 128 + 128; s += 4) {
    const float* rowp = memv + (size_t)s * 600;
    float acc = 0.f;
    for (int d = lane; d < 600; d += 64) acc += rowp[d] * aW[d];
    for (int off = 32; off; off >>= 1) acc += __shfl_xor(acc, off);
    if (lane == 0) {
      float p = (float)s;
      bool inl = p < ll;
      bool inr = (p >= ll + al) && (p < ml);
      float u = inl ? (p - ll) : (inr ? (p - ll - al + 1.f) : 0.f);
      scg[s] = acc + u * aW[600];
    }
  }
}

// ---------------- K6: softmax + weighted sum -> i^T ----------------
__global__ __launch_bounds__(256) void attn_kernel(char* __restrict__ ws) {
  const int bid = blockIdx.x;
  const int b = bid >> 1, dh = bid & 1;
  const int tid = threadIdx.x, wv = tid >> 6, lane = tid & 63;
  __shared__ float alpha[256];
  __shared__ float red[8];
  const float* scg = (const float*)(ws + oSc) + b * S_;
  float v = scg[tid];
  float mx = v;
  for (int off = 32; off; off >>= 1) mx = fmaxf(mx, __shfl_xor(mx, off));
  if (lane == 0) red[wv] = mx;
  __syncthreads();
  mx = fmaxf(fmaxf(red[0], red[1]), fmaxf(red[2], red[3]));
  float e = __expf(v - mx);
  float sm = e;
  for (int off = 32; off; off >>= 1) sm += __shfl_xor(sm, off);
  if (lane == 0) red[4 + wv] = sm;
  __syncthreads();
  float tot = red[4] + red[5] + red[6] + red[7];
  alpha[tid] = e / tot;
  const float ml = (float)((const int*)(ws + oLens))[b];
  const float ll = (float)((const int*)(ws + oLens + 512))[b];
  const float al = (float)((const int*)(ws + oLens + 1024))[b];
  __syncthreads();
  const float* memv = (const float*)(ws + oMemV) + (size_t)b * S_ * 600;
  float* iT = (float*)(ws + oIT);
  const int d0 = dh * 301, d1 = dh ? 601 : 301;
  for (int d = d0 + tid; d < d1; d += 256) {
    float acc = 0.f;
    if (d < 600) {
      for (int s = 0; s < 256; ++s) acc += alpha[s] * memv[(size_t)s * 600 + d];
    } else {
      for (int s = 0; s < 256; ++s) {
        float p = (float)s;
        bool inl = p < ll;
        bool inr = (p >= ll + al) && (p < ml);
        float u = inl ? (p - ll) : (inr ? (p - ll - al + 1.f) : 0.f);
        acc += alpha[s] * u;
      }
    }
    iT[d * 128 + b] = acc;
  }
}

// ---------------- K7: GRU gi (once) ----------------
__global__ __launch_bounds__(256) void gi_kernel(const float* __restrict__ Wih,
                                                 const float* __restrict__ bih,
                                                 char* __restrict__ ws) {
  int idx = blockIdx.x * 256 + threadIdx.x;
  int r = idx >> 7, b = idx & 127;
  if (r >= 900) return;
  const float* iT = (const float*)(ws + oIT);
  const float* wr = Wih + (size_t)r * 601;
  float acc = bih[r];
  for (int d = 0; d < 601; ++d) acc += iT[d * 128 + b] * wr[d];
  ((float*)(ws + oGi))[r * 128 + b] = acc;
}

// ---------------- K8: GRU gh (per hop) ----------------
__global__ __launch_bounds__(256) void gh_kernel(const float* __restrict__ Whh,
                                                 const float* __restrict__ bhh,
                                                 char* __restrict__ ws) {
  int idx = blockIdx.x * 256 + threadIdx.x;
  int r = idx >> 7, b = idx & 127;
  if (r >= 900) return;
  const float* et = (const float*)(ws + oEt);
  const float* wr = Whh + (size_t)r * 300;
  float acc = bhh[r];
  for (int u = 0; u < 300; ++u) acc += et[u * 128 + b] * wr[u];
  ((float*)(ws + oGh))[r * 128 + b] = acc;
}

// ---------------- K9: GRU update (per hop) ----------------
__global__ __launch_bounds__(256) void up_kernel(char* __restrict__ ws) {
  int idx = blockIdx.x * 256 + threadIdx.x;
  int u = idx >> 7, b = idx & 127;
  if (u >= 300) return;
  const float* gi = (const float*)(ws + oGi);
  const float* gh = (const float*)(ws + oGh);
  float* et = (float*)(ws + oEt);
  float rr = sigm(gi[u * 128 + b] + gh[u * 128 + b]);
  float zz = sigm(gi[(300 + u) * 128 + b] + gh[(300 + u) * 128 + b]);
  float nn = tanh_f(gi[(600 + u) * 128 + b] + rr * gh[(600 + u) * 128 + b]);
  float old = et[u * 128 + b];
  et[u * 128 + b] = (1.f - zz) * nn + zz * old;
}

// ---------------- K10: dense head ----------------
__global__ __launch_bounds__(384) void dense_kernel(const float* __restrict__ dW,
                                                    const float* __restrict__ dB,
                                                    float* __restrict__ out,
                                                    const char* __restrict__ ws) {
  int tid = threadIdx.x;
  if (tid >= 384) return;
  int b = tid / 3, c = tid - 3 * (tid / 3);
  const float* et = (const float*)(ws + oEt);
  float acc = dB[c];
  const float* wr = dW + c * 300;
  for (int u = 0; u < 300; ++u) acc += et[u * 128 + b] * wr[u];
  out[b * 3 + c] = acc;
}

extern "C" void kernel_launch(void* const* d_in, const int* in_sizes, int n_in,
                              void* d_out, int out_size, void* d_ws, size_t ws_size,
                              hipStream_t stream) {
  const int* text = (const int*)d_in[0];
  const int* aspect = (const int*)d_in[1];
  const int* leftc = (const int*)d_in[2];
  const float* emb = (const float*)d_in[3];
  const float* WihF = (const float*)d_in[4];
  const float* WhhF = (const float*)d_in[5];
  const float* bihF = (const float*)d_in[6];
  const float* bhhF = (const float*)d_in[7];
  const float* WihB = (const float*)d_in[8];
  const float* WhhB = (const float*)d_in[9];
  const float* bihB = (const float*)d_in[10];
  const float* bhhB = (const float*)d_in[11];
  const float* attW = (const float*)d_in[12];
  const float* gruWih = (const float*)d_in[14];
  const float* gruWhh = (const float*)d_in[15];
  const float* gruBih = (const float*)d_in[16];
  const float* gruBhh = (const float*)d_in[17];
  const float* denseW = (const float*)d_in[18];
  const float* denseB = (const float*)d_in[19];
  float* out = (float*)d_out;
  char* ws = (char*)d_ws;
  if (ws_size < WS_NEED) return;

  init_kernel<<<67, 256, 0, stream>>>(text, aspect, leftc, ws);
  pack_kernel<<<7212, 256, 0, stream>>>(WihF, WhhF, bihF, bhhF, WihB, WhhB, bihB, bhhB, ws);
  gather_kernel<<<2 * B_ * S_, KPAD, 0, stream>>>(text, emb, ws);
  lstm_kernel<<<NBLK, 512, 0, stream>>>(ws);
  score_kernel<<<2 * B_, 256, 0, stream>>>(attW, ws);
  attn_kernel<<<2 * B_, 256, 0, stream>>>(ws);
  gi_kernel<<<450, 256, 0, stream>>>(gruWih, gruBih, ws);
  for (int h = 0; h < 3; ++h) {
    gh_kernel<<<450, 256, 0, stream>>>(gruWhh, gruBhh, ws);
    up_kernel<<<150, 256, 0, stream>>>(ws);
  }
  dense_kernel<<<1, 384, 0, stream>>>(denseW, denseB, out, ws);
}